// Round 1
// baseline (99.508 us; speedup 1.0000x reference)
//
#include <hip/hip_runtime.h>

// Problem constants (from reference): B=2, N=2048, F_IN=128, H=8, F=32
constexpr int Bv  = 2;
constexpr int Nv  = 2048;
constexpr int FIN = 128;
constexpr int Hn  = 8;
constexpr int Fv  = 32;

// ---------------------------------------------------------------------------
// Kernel 1: wa[which][k][h] = sum_f w[k, h*F+f] * a[which*F + f]
//   which=0 -> a1 (s_j weights), which=1 -> a2 (s_i weights)
//   wa layout: 2*128*8 = 2048 floats
// ---------------------------------------------------------------------------
__global__ void compute_wa(const float* __restrict__ w,
                           const float* __restrict__ a,
                           float* __restrict__ wa) {
    int t = blockIdx.x * blockDim.x + threadIdx.x;   // 0..2047
    if (t >= 2 * FIN * Hn) return;
    int which = t >> 10;          // 0 or 1
    int k     = (t >> 3) & (FIN - 1);
    int h     = t & (Hn - 1);
    const float* ap = a + which * Fv;
    const float* wp = w + (size_t)k * (Fv * Hn) + h * Fv;
    float s = 0.f;
    #pragma unroll
    for (int f = 0; f < Fv; ++f) s = fmaf(wp[f], ap[f], s);
    wa[t] = s;
}

// ---------------------------------------------------------------------------
// Kernel 2: s_j[row][h] = sum_k x[row][k]*wa1[k][h]
//           s_i[row][h] = sum_k x[row][k]*wa2[k][h]
//   row = b*N+n in [0, 8192); s layout: [s_j (32768 floats)][s_i (32768)]
// ---------------------------------------------------------------------------
__global__ void compute_s(const float* __restrict__ x,
                          const float* __restrict__ wa,
                          float* __restrict__ s) {
    int t = blockIdx.x * blockDim.x + threadIdx.x;   // row*8 + h
    int h   = t & (Hn - 1);
    int row = t >> 3;
    if (row >= Bv * Nv) return;
    const float* xr = x + (size_t)row * FIN;
    const float* w1 = wa + h;                 // wa1[k][h], stride Hn
    const float* w2 = wa + FIN * Hn + h;      // wa2[k][h]
    float sj = 0.f, si = 0.f;
    #pragma unroll 8
    for (int k = 0; k < FIN; ++k) {
        float xv = xr[k];
        sj = fmaf(xv, w1[k * Hn], sj);
        si = fmaf(xv, w2[k * Hn], si);
    }
    s[t] = sj;
    s[(size_t)Bv * Nv * Hn + t] = si;
}

// ---------------------------------------------------------------------------
// Kernel 3: main. One block per output row (b,i).
//   Phase 1: norm[h] = sum_j g[b,i,j] * exp(lrelu(s_i[b,i,h]+s_j[b,j,h]))
//   Phase 2: out[b,i,j,h] = exp(lrelu(...)) * (1/norm[h])
// ---------------------------------------------------------------------------
__global__ __launch_bounds__(256) void attn_out(const float* __restrict__ g,
                                                const float* __restrict__ s,
                                                float* __restrict__ out) {
    const int row = blockIdx.x;        // b*N + i
    const int b   = row >> 11;         // N = 2048
    const int tid = threadIdx.x;

    const float* sj_base = s + (size_t)b * Nv * Hn;
    const float* si_p    = s + (size_t)Bv * Nv * Hn + (size_t)row * Hn;

    float si[Hn];
    #pragma unroll
    for (int h = 0; h < Hn; ++h) si[h] = si_p[h];  // 32B broadcast, L1-hit

    const float* grow = g + (size_t)row * Nv;

    float norm[Hn];
    #pragma unroll
    for (int h = 0; h < Hn; ++h) norm[h] = 0.f;

    // ---- phase 1: accumulate norm (branchless; g is ~5% nonzero but VALU
    // cycles are paid per-issue anyway; loads stay L2-resident) ----
    for (int j = tid; j < Nv; j += 256) {
        float gv = grow[j];
        const float4* sj4 = (const float4*)(sj_base + (size_t)j * Hn);
        float4 v0 = sj4[0], v1 = sj4[1];
        float sjv[Hn] = {v0.x, v0.y, v0.z, v0.w, v1.x, v1.y, v1.z, v1.w};
        #pragma unroll
        for (int h = 0; h < Hn; ++h) {
            float sc = si[h] + sjv[h];
            sc = sc >= 0.f ? sc : 0.2f * sc;       // leaky_relu(0.2)
            norm[h] = fmaf(gv, __expf(sc), norm[h]);
        }
    }

    // ---- block reduction of norm[8] over 4 waves ----
    __shared__ float red[4][Hn];
    __shared__ float rnorm[Hn];
    const int lane = tid & 63, wv = tid >> 6;
    #pragma unroll
    for (int h = 0; h < Hn; ++h) {
        float v = norm[h];
        #pragma unroll
        for (int off = 32; off > 0; off >>= 1) v += __shfl_down(v, off);
        if (lane == 0) red[wv][h] = v;
    }
    __syncthreads();
    if (tid < Hn) {
        float v = red[0][tid] + red[1][tid] + red[2][tid] + red[3][tid];
        rnorm[tid] = 1.0f / v;   // norm > 0 guaranteed (diag of g is 1)
    }
    __syncthreads();

    float rn[Hn];
    #pragma unroll
    for (int h = 0; h < Hn; ++h) rn[h] = rnorm[h];

    // ---- phase 2: recompute e, write out (coalesced float4 x2 per j) ----
    float* orow = out + (size_t)row * Nv * Hn;
    for (int j = tid; j < Nv; j += 256) {
        const float4* sj4 = (const float4*)(sj_base + (size_t)j * Hn);
        float4 v0 = sj4[0], v1 = sj4[1];
        float sjv[Hn] = {v0.x, v0.y, v0.z, v0.w, v1.x, v1.y, v1.z, v1.w};
        float ov[Hn];
        #pragma unroll
        for (int h = 0; h < Hn; ++h) {
            float sc = si[h] + sjv[h];
            sc = sc >= 0.f ? sc : 0.2f * sc;
            ov[h] = __expf(sc) * rn[h];
        }
        float4* o4 = (float4*)(orow + (size_t)j * Hn);
        o4[0] = make_float4(ov[0], ov[1], ov[2], ov[3]);
        o4[1] = make_float4(ov[4], ov[5], ov[6], ov[7]);
    }
}

// ---------------------------------------------------------------------------
extern "C" void kernel_launch(void* const* d_in, const int* in_sizes, int n_in,
                              void* d_out, int out_size, void* d_ws, size_t ws_size,
                              hipStream_t stream) {
    const float* g = (const float*)d_in[0];   // (B,N,N)
    const float* x = (const float*)d_in[1];   // (B,N,F_IN)
    const float* w = (const float*)d_in[2];   // (F_IN, F*H)
    const float* a = (const float*)d_in[3];   // (2F,)
    // d_in[4] = n_heads (int scalar) -- hardcoded H=8

    float* ws = (float*)d_ws;
    float* wa = ws;                 // 2048 floats
    float* s  = ws + 2 * FIN * Hn;  // 2*8192*8 = 65536 floats

    float* out = (float*)d_out;     // (B,N,N,H) fp32, 268 MB

    compute_wa<<<(2 * FIN * Hn + 255) / 256, 256, 0, stream>>>(w, a, wa);
    compute_s<<<(Bv * Nv * Hn + 255) / 256, 256, 0, stream>>>(x, wa, s);
    attn_out<<<Bv * Nv, 256, 0, stream>>>(g, s, out);
}